// Round 2
// baseline (1179.683 us; speedup 1.0000x reference)
//
#include <hip/hip_runtime.h>
#include <hip/hip_bf16.h>
#include <math.h>

#define NNODES   8192
#define DIN      768
#define DSTRUCT  32
#define XDIM     800     // DIN + DSTRUCT
#define DHID     768
#define DOUT     768
#define MEMK     64
#define NGRAPH   64
#define BUCKET_CAP 128

// ---------------- workspace layout (bytes, 256-aligned) ----------------
#define OFF_X       0u                        // X [8192,800] f32, later reused as node_feats
#define SZ_X        (8192u*800u*4u)           // 26,214,400
#define OFF_H       (OFF_X + SZ_X)            // h [8192,768]
#define SZ_H        (8192u*768u*4u)           // 25,165,824
#define OFF_BUCKET  (OFF_H + SZ_H)            // bucket [8192,128] int
#define SZ_BUCKET   (8192u*BUCKET_CAP*4u)     // 4,194,304
#define OFF_COUNTS  (OFF_BUCKET + SZ_BUCKET)  // counts [8192] int
#define SZ_COUNTS   (8192u*4u)
#define OFF_GSTART  (OFF_COUNTS + SZ_COUNTS)  // [64] int (padded 256)
#define OFF_GEND    (OFF_GSTART + 256u)
#define OFF_LOSS    (OFF_GEND + 256u)         // f32 accumulator (padded 256)
#define OFF_SCORES  (OFF_LOSS + 256u)         // scores/weights [8192,64] f32
#define SZ_SCORES   (8192u*64u*4u)
#define OFF_GFEAT   (OFF_SCORES + SZ_SCORES)  // graph_feats [64,768]
#define OFF_T1      (OFF_GFEAT + 64u*768u*4u) // tanh hidden [64,768]
#define OFF_MEMT    (OFF_T1 + 64u*768u*4u)    // memory^T [768,64]

// zeroed each call: counts + gstart + gend + loss  (contiguous)
#define ZERO_OFF    OFF_COUNTS
#define ZERO_BYTES  (SZ_COUNTS + 256u + 256u + 256u)

// ---------------- CSR build ----------------
__global__ void k_fill_bucket(const int* __restrict__ col, int* __restrict__ counts,
                              int* __restrict__ bucket, int E) {
    for (int e = blockIdx.x * blockDim.x + threadIdx.x; e < E; e += gridDim.x * blockDim.x) {
        int c = col[e];
        if ((unsigned)c < (unsigned)NNODES) {
            int p = atomicAdd(&counts[c], 1);
            if (p < BUCKET_CAP) bucket[c * BUCKET_CAP + p] = e;
        }
    }
}

// ---------------- aggregate edges + build X = [feat | struct_feat] ----------------
__global__ __launch_bounds__(192) void k_aggregate(
    const float* __restrict__ feature, const float* __restrict__ edge_attr,
    const float* __restrict__ ppr, const float* __restrict__ Ws, const float* __restrict__ bs,
    const int* __restrict__ bucket, const int* __restrict__ counts,
    float* __restrict__ X) {
    int n = blockIdx.x;
    int t = threadIdx.x;            // 192 threads, one float4 each over 768 dims
    const float4* frow = (const float4*)(feature + (size_t)n * DIN);
    float4 acc = frow[t];
    int deg = min(counts[n], BUCKET_CAP);
    const int* bk = bucket + n * BUCKET_CAP;
    for (int j = 0; j < deg; ++j) {
        int e = bk[j];
        float4 v = ((const float4*)(edge_attr + (size_t)e * DIN))[t];
        acc.x += v.x; acc.y += v.y; acc.z += v.z; acc.w += v.w;
    }
    float* Xrow = X + (size_t)n * XDIM;
    ((float4*)Xrow)[t] = acc;
    if (t < DSTRUCT / 4) {           // struct features: relu(ppr*Ws + bs)
        float p = ppr[n];
        int k = t * 4;
        float4 s;
        s.x = fmaxf(p * Ws[k+0] + bs[k+0], 0.f);
        s.y = fmaxf(p * Ws[k+1] + bs[k+1], 0.f);
        s.z = fmaxf(p * Ws[k+2] + bs[k+2], 0.f);
        s.w = fmaxf(p * Ws[k+3] + bs[k+3], 0.f);
        *(float4*)(Xrow + DIN + k) = s;
    }
}

// ---------------- generic f32 tiled GEMM:  C = act(scale * (A@B) + bias) ----------------
// A [M,K] rm, B [K,N] rm, C [M,N] rm.  BM=BN=128, BK=8, 256 thr, 8x8/thread.
// ACT: 0 none, 1 prelu, 2 tanh
__device__ __forceinline__ int bswz(int w) { return w ^ (((w >> 5) & 3) << 2); }

template<int ACT>
__global__ __launch_bounds__(256) void k_gemm(
    const float* __restrict__ A, const float* __restrict__ B,
    const float* __restrict__ bias, float* __restrict__ C,
    int M, int N, int K, float scale, const float* __restrict__ act_p) {
    __shared__ float As[8][128];
    __shared__ float Bs[8][128];
    int tid = threadIdx.x;
    int n0 = blockIdx.x * 128, m0 = blockIdx.y * 128;
    int tx = tid & 15, ty = tid >> 4;
    int arow = tid >> 1;
    int akq  = (tid & 1) * 4;
    int brow = tid >> 5;
    int bcol = (tid & 31) * 4;
    float acc[8][8];
#pragma unroll
    for (int i = 0; i < 8; ++i)
#pragma unroll
        for (int j = 0; j < 8; ++j) acc[i][j] = 0.f;

    for (int k0 = 0; k0 < K; k0 += 8) {
        float4 av = make_float4(0.f, 0.f, 0.f, 0.f);
        if (m0 + arow < M) av = *(const float4*)(A + (size_t)(m0 + arow) * K + k0 + akq);
        As[akq + 0][arow] = av.x; As[akq + 1][arow] = av.y;
        As[akq + 2][arow] = av.z; As[akq + 3][arow] = av.w;
        float4 bv = make_float4(0.f, 0.f, 0.f, 0.f);
        if (n0 + bcol < N) bv = *(const float4*)(B + (size_t)(k0 + brow) * N + n0 + bcol);
        *(float4*)(&Bs[brow][bswz(bcol)]) = bv;
        __syncthreads();
#pragma unroll
        for (int kk = 0; kk < 8; ++kk) {
            float a[8], b[8];
            *(float4*)&a[0] = *(float4*)&As[kk][ty * 8];
            *(float4*)&a[4] = *(float4*)&As[kk][ty * 8 + 4];
            *(float4*)&b[0] = *(float4*)&Bs[kk][bswz(tx * 8)];
            *(float4*)&b[4] = *(float4*)&Bs[kk][bswz(tx * 8 + 4)];
#pragma unroll
            for (int i = 0; i < 8; ++i)
#pragma unroll
                for (int j = 0; j < 8; ++j) acc[i][j] = fmaf(a[i], b[j], acc[i][j]);
        }
        __syncthreads();
    }

    float ap = (ACT == 1 && act_p) ? *act_p : 0.f;
#pragma unroll
    for (int i = 0; i < 8; ++i) {
        int row = m0 + ty * 8 + i;
        if (row >= M) continue;
        float* Crow = C + (size_t)row * N;
#pragma unroll
        for (int jq = 0; jq < 2; ++jq) {
            int col = n0 + tx * 8 + jq * 4;
            if (col >= N) continue;
            float4 v;
            float* pv = &v.x;
#pragma unroll
            for (int l = 0; l < 4; ++l) {
                float x = acc[i][jq * 4 + l] * scale;
                if (bias) x += bias[col + l];
                if (ACT == 1) x = x > 0.f ? x : ap * x;
                if (ACT == 2) x = tanhf(x);
                pv[l] = x;
            }
            *(float4*)(Crow + col) = v;
        }
    }
}

// ---------------- graph boundaries (batch_ids sorted) ----------------
__global__ void k_boundaries(const int* __restrict__ batch, int* __restrict__ gstart,
                             int* __restrict__ gend, int n) {
    int i = blockIdx.x * blockDim.x + threadIdx.x;
    if (i >= n) return;
    int b = batch[i];
    if ((unsigned)b >= (unsigned)NGRAPH) return;
    if (i == 0 || batch[i - 1] != b) gstart[b] = i;
    if (i == n - 1 || batch[i + 1] != b) gend[b] = i + 1;
}

// ---------------- scatter-mean pooling ----------------
__global__ __launch_bounds__(192) void k_pool(const float* __restrict__ nf,
                                              const int* __restrict__ gstart, const int* __restrict__ gend,
                                              float* __restrict__ gfeat) {
    int g = blockIdx.x, t = threadIdx.x;
    int s = gstart[g], e = gend[g];
    float4 acc = make_float4(0.f, 0.f, 0.f, 0.f);
    for (int n = s; n < e; ++n) {
        float4 v = ((const float4*)(nf + (size_t)n * DOUT))[t];
        acc.x += v.x; acc.y += v.y; acc.z += v.z; acc.w += v.w;
    }
    float inv = 1.f / fmaxf((float)(e - s), 1.f);
    acc.x *= inv; acc.y *= inv; acc.z *= inv; acc.w *= inv;
    ((float4*)(gfeat + (size_t)g * DOUT))[t] = acc;
}

// ---------------- memory^T ----------------
__global__ void k_transpose_mem(const float* __restrict__ mem, float* __restrict__ memT) {
    int idx = blockIdx.x * blockDim.x + threadIdx.x;
    if (idx >= MEMK * 768) return;
    int k = idx & (MEMK - 1);
    int d = idx >> 6;
    memT[idx] = mem[k * 768 + d];
}

// ---------------- row softmax over 64 slots ----------------
__global__ void k_softmax(float* __restrict__ scores, int rows) {
    int row = blockIdx.x * 4 + (threadIdx.x >> 6);
    int lane = threadIdx.x & 63;
    if (row >= rows) return;
    float s = scores[row * 64 + lane];
    float m = s;
    for (int o = 32; o > 0; o >>= 1) m = fmaxf(m, __shfl_xor(m, o, 64));
    float e = __expf(s - m);
    float sum = e;
    for (int o = 32; o > 0; o >>= 1) sum += __shfl_xor(sum, o, 64);
    scores[row * 64 + lane] = e / sum;
}

// ---------------- MSE loss ----------------
__global__ void k_loss(const float* __restrict__ nf, const float* __restrict__ re,
                       float* __restrict__ acc, int n4) {
    float p = 0.f;
    for (int i = blockIdx.x * blockDim.x + threadIdx.x; i < n4; i += gridDim.x * blockDim.x) {
        float4 a = ((const float4*)nf)[i];
        float4 b = ((const float4*)re)[i];
        float dx = a.x - b.x, dy = a.y - b.y, dz = a.z - b.z, dw = a.w - b.w;
        p += dx * dx + dy * dy + dz * dz + dw * dw;
    }
    for (int o = 32; o > 0; o >>= 1) p += __shfl_xor(p, o, 64);
    __shared__ float red[4];
    if ((threadIdx.x & 63) == 0) red[threadIdx.x >> 6] = p;
    __syncthreads();
    if (threadIdx.x == 0) atomicAdd(acc, red[0] + red[1] + red[2] + red[3]);
}

__global__ void k_loss_final(const float* __restrict__ acc, float* __restrict__ out, float invn) {
    if (threadIdx.x == 0 && blockIdx.x == 0) out[0] = acc[0] * invn;
}

// ---------------- launch ----------------
extern "C" void kernel_launch(void* const* d_in, const int* in_sizes, int n_in,
                              void* d_out, int out_size, void* d_ws, size_t ws_size,
                              hipStream_t stream) {
    const float* feature  = (const float*)d_in[0];
    const float* ppr      = (const float*)d_in[1];
    const float* edge_attr= (const float*)d_in[2];
    const float* Ws       = (const float*)d_in[3];
    const float* bs       = (const float*)d_in[4];
    const float* W1       = (const float*)d_in[5];
    const float* b1       = (const float*)d_in[6];
    const float* prelu_a  = (const float*)d_in[7];
    const float* W2       = (const float*)d_in[8];
    const float* b2       = (const float*)d_in[9];
    const float* Wp1      = (const float*)d_in[10];
    const float* bp1      = (const float*)d_in[11];
    const float* Wp2      = (const float*)d_in[12];
    const float* bp2      = (const float*)d_in[13];
    const float* memory   = (const float*)d_in[14];
    const int*   edge_index = (const int*)d_in[15];
    const int*   batch_ids  = (const int*)d_in[16];

    const int E = in_sizes[15] / 2;
    const int N = in_sizes[0] / DIN;
    const int* col = edge_index + E;   // edge_index[1]

    char* ws = (char*)d_ws;
    float* X      = (float*)(ws + OFF_X);        // X, later node_feats
    float* h      = (float*)(ws + OFF_H);
    int*   bucket = (int*)  (ws + OFF_BUCKET);
    int*   counts = (int*)  (ws + OFF_COUNTS);
    int*   gstart = (int*)  (ws + OFF_GSTART);
    int*   gend   = (int*)  (ws + OFF_GEND);
    float* lossac = (float*)(ws + OFF_LOSS);
    float* scores = (float*)(ws + OFF_SCORES);
    float* gfeat  = (float*)(ws + OFF_GFEAT);
    float* t1     = (float*)(ws + OFF_T1);
    float* memT   = (float*)(ws + OFF_MEMT);

    float* out_pooled = (float*)d_out;                       // [64,768]
    float* out_re     = (float*)d_out + NGRAPH * DOUT;       // [8192,768]
    float* out_loss   = (float*)d_out + NGRAPH * DOUT + (size_t)N * DOUT;

    (void)hipMemsetAsync(ws + ZERO_OFF, 0, ZERO_BYTES, stream);

    k_fill_bucket<<<1024, 256, 0, stream>>>(col, counts, bucket, E);
    k_aggregate<<<N, 192, 0, stream>>>(feature, edge_attr, ppr, Ws, bs, bucket, counts, X);

    // h = prelu(X @ W1 + b1)
    k_gemm<1><<<dim3(DHID / 128, N / 128), 256, 0, stream>>>(X, W1, b1, h, N, DHID, XDIM, 1.f, prelu_a);
    // node_feats = h @ W2 + b2   (reuse X buffer)
    float* nf = X;
    k_gemm<0><<<dim3(DOUT / 128, N / 128), 256, 0, stream>>>(h, W2, b2, nf, N, DOUT, DHID, 1.f, nullptr);

    k_boundaries<<<(N + 255) / 256, 256, 0, stream>>>(batch_ids, gstart, gend, N);
    k_pool<<<NGRAPH, 192, 0, stream>>>(nf, gstart, gend, gfeat);

    // pooled = tanh(gfeat @ Wp1 + bp1) @ Wp2 + bp2
    k_gemm<2><<<dim3(DHID / 128, 1), 256, 0, stream>>>(gfeat, Wp1, bp1, t1, NGRAPH, DHID, DHID, 1.f, nullptr);
    k_gemm<0><<<dim3(DOUT / 128, 1), 256, 0, stream>>>(t1, Wp2, bp2, out_pooled, NGRAPH, DOUT, DHID, 1.f, nullptr);

    // attention: scores = nf @ memory^T ; softmax ; re = (w @ memory)/64
    k_transpose_mem<<<(MEMK * 768 + 255) / 256, 256, 0, stream>>>(memory, memT);
    k_gemm<0><<<dim3(1, N / 128), 256, 0, stream>>>(nf, memT, nullptr, scores, N, MEMK, DOUT, 1.f, nullptr);
    k_softmax<<<(N + 3) / 4, 256, 0, stream>>>(scores, N);
    k_gemm<0><<<dim3(DOUT / 128, N / 128), 256, 0, stream>>>(scores, memory, nullptr, out_re, N, DOUT, MEMK, 1.f / 64.f, nullptr);

    // loss = mean((nf - re)^2)
    k_loss<<<2048, 256, 0, stream>>>(nf, out_re, lossac, (N * DOUT) / 4);
    k_loss_final<<<1, 64, 0, stream>>>(lossac, out_loss, 1.f / (float)(N * DOUT));
}

// Round 3
// 714.787 us; speedup vs baseline: 1.6504x; 1.6504x over previous
//
#include <hip/hip_runtime.h>
#include <hip/hip_bf16.h>
#include <math.h>

typedef unsigned short ushort_t;
typedef short bf16x8 __attribute__((ext_vector_type(8)));
typedef float f32x4 __attribute__((ext_vector_type(4)));

#define NNODES   8192
#define DIN      768
#define DSTRUCT  32
#define XDIM     800
#define DHID     768
#define DOUT     768
#define MEMK     64
#define NGRAPH   64
#define BUCKET_CAP 128

// ---------------- workspace layout (bytes, 256-aligned) ----------------
#define OFF_XHI     0u
#define OFF_XLO     (OFF_XHI + 8192u*800u*2u)     // 13,107,200
#define OFF_HHI     (OFF_XLO + 8192u*800u*2u)
#define OFF_HLO     (OFF_HHI + 8192u*768u*2u)
#define OFF_NF      (OFF_HLO + 8192u*768u*2u)     // f32 [8192][768]
#define OFF_W1THI   (OFF_NF + 8192u*768u*4u)
#define OFF_W1TLO   (OFF_W1THI + 768u*800u*2u)
#define OFF_W2THI   (OFF_W1TLO + 768u*800u*2u)
#define OFF_W2TLO   (OFF_W2THI + 768u*768u*2u)
#define OFF_BUCKET  (OFF_W2TLO + 768u*768u*2u)
#define OFF_COUNTS  (OFF_BUCKET + 8192u*BUCKET_CAP*4u)
#define OFF_GSTART  (OFF_COUNTS + 8192u*4u)
#define OFF_GEND    (OFF_GSTART + 256u)
#define OFF_LOSS    (OFF_GEND + 256u)
#define OFF_GFEAT   (OFF_LOSS + 256u)
#define OFF_T1      (OFF_GFEAT + 64u*768u*4u)
#define ZERO_OFF    OFF_COUNTS
#define ZERO_BYTES  (8192u*4u + 256u + 256u + 256u)

// ---------------- helpers ----------------
__device__ __forceinline__ ushort_t bf_rne(float f) {
    unsigned u = __float_as_uint(f);
    return (ushort_t)((u + 0x7FFFu + ((u >> 16) & 1u)) >> 16);
}
__device__ __forceinline__ void split_bf16(float f, ushort_t& hi, ushort_t& lo) {
    ushort_t h = bf_rne(f);
    float fh = __uint_as_float(((unsigned)h) << 16);
    hi = h;
    lo = bf_rne(f - fh);
}
__device__ __forceinline__ void gld16(const void* g, void* l) {
    __builtin_amdgcn_global_load_lds(
        (const __attribute__((address_space(1))) unsigned int*)g,
        (__attribute__((address_space(3))) unsigned int*)l, 16, 0, 0);
}

// ---------------- CSR build ----------------
__global__ void k_fill_bucket(const int* __restrict__ col, int* __restrict__ counts,
                              int* __restrict__ bucket, int E) {
    for (int e = blockIdx.x * blockDim.x + threadIdx.x; e < E; e += gridDim.x * blockDim.x) {
        int c = col[e];
        if ((unsigned)c < (unsigned)NNODES) {
            int p = atomicAdd(&counts[c], 1);
            if (p < BUCKET_CAP) bucket[c * BUCKET_CAP + p] = e;
        }
    }
}

// ---------------- aggregate edges -> X planes (bf16 hi/lo) ----------------
__global__ __launch_bounds__(192) void k_aggregate(
    const float* __restrict__ feature, const float* __restrict__ edge_attr,
    const float* __restrict__ ppr, const float* __restrict__ Ws, const float* __restrict__ bs,
    const int* __restrict__ bucket, const int* __restrict__ counts,
    ushort_t* __restrict__ Xhi, ushort_t* __restrict__ Xlo) {
    int n = blockIdx.x;
    int t = threadIdx.x;
    const float4* frow = (const float4*)(feature + (size_t)n * DIN);
    float4 acc = frow[t];
    int deg = min(counts[n], BUCKET_CAP);
    const int* bk = bucket + n * BUCKET_CAP;
    for (int j = 0; j < deg; ++j) {
        int e = bk[j];
        float4 v = ((const float4*)(edge_attr + (size_t)e * DIN))[t];
        acc.x += v.x; acc.y += v.y; acc.z += v.z; acc.w += v.w;
    }
    ushort4 h4, l4;
    split_bf16(acc.x, h4.x, l4.x); split_bf16(acc.y, h4.y, l4.y);
    split_bf16(acc.z, h4.z, l4.z); split_bf16(acc.w, h4.w, l4.w);
    *(ushort4*)(Xhi + (size_t)n * XDIM + t * 4) = h4;
    *(ushort4*)(Xlo + (size_t)n * XDIM + t * 4) = l4;
    if (t < DSTRUCT / 4) {
        float p = ppr[n];
        int k = t * 4;
        float4 s;
        s.x = fmaxf(p * Ws[k+0] + bs[k+0], 0.f);
        s.y = fmaxf(p * Ws[k+1] + bs[k+1], 0.f);
        s.z = fmaxf(p * Ws[k+2] + bs[k+2], 0.f);
        s.w = fmaxf(p * Ws[k+3] + bs[k+3], 0.f);
        ushort4 sh, sl;
        split_bf16(s.x, sh.x, sl.x); split_bf16(s.y, sh.y, sl.y);
        split_bf16(s.z, sh.z, sl.z); split_bf16(s.w, sh.w, sl.w);
        *(ushort4*)(Xhi + (size_t)n * XDIM + DIN + k) = sh;
        *(ushort4*)(Xlo + (size_t)n * XDIM + DIN + k) = sl;
    }
}

// ---------------- weight transpose + split:  W[K][N] f32 -> T_hi/lo[N][K] bf16 ----------------
__global__ __launch_bounds__(256) void k_wsplit(const float* __restrict__ W,
                                                ushort_t* __restrict__ Thi, ushort_t* __restrict__ Tlo,
                                                int K, int N) {
    __shared__ float tile[32][33];
    int n0 = blockIdx.x * 32, k0 = blockIdx.y * 32;
    int tx = threadIdx.x & 31, ty = threadIdx.x >> 5;
#pragma unroll
    for (int i = 0; i < 4; ++i) {
        int k = ty + i * 8;
        tile[k][tx] = W[(size_t)(k0 + k) * N + n0 + tx];
    }
    __syncthreads();
#pragma unroll
    for (int i = 0; i < 4; ++i) {
        int nn = ty + i * 8;
        float v = tile[tx][nn];
        ushort_t hi, lo; split_bf16(v, hi, lo);
        Thi[(size_t)(n0 + nn) * K + k0 + tx] = hi;
        Tlo[(size_t)(n0 + nn) * K + k0 + tx] = lo;
    }
}

// ---------------- split-bf16 MFMA GEMM ----------------
// C[M][N] = act(A@B^T + bias);  A planes [M][K], BT planes [N][K] (bf16 hi/lo)
// BM=64 BN=128 BK=32, 256 thr = 4 waves (2M x 2N), wave tile 32x64.
// LDS per buf (ushort units): Ahi[4][64][8] | Alo | Bhi[4][128][8] | Blo
#define L_AHI 0
#define L_ALO 2048
#define L_BHI 4096
#define L_BLO 8192
#define L_BUF 12288

template<int ACT, int OUTPLANES>   // ACT: 0 none, 1 prelu ; OUTPLANES: 1 -> write hi/lo planes else f32
__global__ __launch_bounds__(256) void k_gemm_mfma(
    const ushort_t* __restrict__ Ahi, const ushort_t* __restrict__ Alo,
    const ushort_t* __restrict__ Bhi, const ushort_t* __restrict__ Blo,
    const float* __restrict__ bias, const float* __restrict__ act_p,
    float* __restrict__ Cf, ushort_t* __restrict__ Chi, ushort_t* __restrict__ Clo,
    int M, int N, int K) {
    __shared__ ushort_t lds[2 * L_BUF];
    int tid = threadIdx.x;
    int l = tid & 63, w = tid >> 6;

    // XCD-aware block swizzle (grid size multiple of 8)
    int nbx = N / 128;
    int nwg = nbx * (M / 64);
    int bid = blockIdx.y * nbx + blockIdx.x;
    int q = nwg >> 3;
    int nb = (bid & 7) * q + (bid >> 3);
    int bx = nb % nbx, by = nb / nbx;
    int m0 = by * 64, n0 = bx * 128;

    int wm = w >> 1, wn = w & 1;

    f32x4 acc[2][4];
#pragma unroll
    for (int m = 0; m < 2; ++m)
#pragma unroll
        for (int n = 0; n < 4; ++n) acc[m][n] = (f32x4){0.f, 0.f, 0.f, 0.f};

    // per-lane global bases (ushort element offsets)
    const ushort_t* agh = Ahi + (size_t)(m0 + l) * K + w * 8;
    const ushort_t* agl = Alo + (size_t)(m0 + l) * K + w * 8;
    int j0 = w, j1 = w + 4;
    const ushort_t* bgh0 = Bhi + (size_t)(n0 + (j0 & 1) * 64 + l) * K + (j0 >> 1) * 8;
    const ushort_t* bgl0 = Blo + (size_t)(n0 + (j0 & 1) * 64 + l) * K + (j0 >> 1) * 8;
    const ushort_t* bgh1 = Bhi + (size_t)(n0 + (j1 & 1) * 64 + l) * K + (j1 >> 1) * 8;
    const ushort_t* bgl1 = Blo + (size_t)(n0 + (j1 & 1) * 64 + l) * K + (j1 >> 1) * 8;

    int NT = K / 32;

    // prologue stage into buf 0
    {
        ushort_t* b = lds;
        gld16(agh, b + L_AHI + w * 512);
        gld16(agl, b + L_ALO + w * 512);
        gld16(bgh0, b + L_BHI + j0 * 512);
        gld16(bgh1, b + L_BHI + j1 * 512);
        gld16(bgl0, b + L_BLO + j0 * 512);
        gld16(bgl1, b + L_BLO + j1 * 512);
    }

    int c0 = l >> 4;
    int arow = wm * 32 + (l & 15);
    int bcol = wn * 64 + (l & 15);

    for (int kt = 0; kt < NT; ++kt) {
        int cur = kt & 1;
        __syncthreads();   // buf[cur] staged (barrier drains vmcnt), prev reads done
        if (kt + 1 < NT) {
            int ko = (kt + 1) * 32;
            ushort_t* b = lds + (cur ^ 1) * L_BUF;
            gld16(agh + ko, b + L_AHI + w * 512);
            gld16(agl + ko, b + L_ALO + w * 512);
            gld16(bgh0 + ko, b + L_BHI + j0 * 512);
            gld16(bgh1 + ko, b + L_BHI + j1 * 512);
            gld16(bgl0 + ko, b + L_BLO + j0 * 512);
            gld16(bgl1 + ko, b + L_BLO + j1 * 512);
        }
        const ushort_t* cb = lds + cur * L_BUF;
        bf16x8 ah[2], al[2], bh[4], bl[4];
#pragma unroll
        for (int m = 0; m < 2; ++m) {
            ah[m] = *(const bf16x8*)(cb + L_AHI + c0 * 512 + (arow + m * 16) * 8);
            al[m] = *(const bf16x8*)(cb + L_ALO + c0 * 512 + (arow + m * 16) * 8);
        }
#pragma unroll
        for (int n = 0; n < 4; ++n) {
            bh[n] = *(const bf16x8*)(cb + L_BHI + c0 * 1024 + (bcol + n * 16) * 8);
            bl[n] = *(const bf16x8*)(cb + L_BLO + c0 * 1024 + (bcol + n * 16) * 8);
        }
#pragma unroll
        for (int m = 0; m < 2; ++m)
#pragma unroll
            for (int n = 0; n < 4; ++n) {
                acc[m][n] = __builtin_amdgcn_mfma_f32_16x16x32_bf16(ah[m], bh[n], acc[m][n], 0, 0, 0);
                acc[m][n] = __builtin_amdgcn_mfma_f32_16x16x32_bf16(ah[m], bl[n], acc[m][n], 0, 0, 0);
                acc[m][n] = __builtin_amdgcn_mfma_f32_16x16x32_bf16(al[m], bh[n], acc[m][n], 0, 0, 0);
            }
    }

    float ap = (ACT == 1) ? *act_p : 0.f;
#pragma unroll
    for (int m = 0; m < 2; ++m)
#pragma unroll
        for (int n = 0; n < 4; ++n) {
            int col = n0 + wn * 64 + n * 16 + (l & 15);
            float bv = bias[col];
#pragma unroll
            for (int r = 0; r < 4; ++r) {
                int row = m0 + wm * 32 + m * 16 + (l >> 4) * 4 + r;
                float x = acc[m][n][r] + bv;
                if (ACT == 1) x = x > 0.f ? x : ap * x;
                if (OUTPLANES) {
                    ushort_t hi, lo; split_bf16(x, hi, lo);
                    Chi[(size_t)row * N + col] = hi;
                    Clo[(size_t)row * N + col] = lo;
                } else {
                    Cf[(size_t)row * N + col] = x;
                }
            }
        }
}

// ---------------- graph boundaries ----------------
__global__ void k_boundaries(const int* __restrict__ batch, int* __restrict__ gstart,
                             int* __restrict__ gend, int n) {
    int i = blockIdx.x * blockDim.x + threadIdx.x;
    if (i >= n) return;
    int b = batch[i];
    if ((unsigned)b >= (unsigned)NGRAPH) return;
    if (i == 0 || batch[i - 1] != b) gstart[b] = i;
    if (i == n - 1 || batch[i + 1] != b) gend[b] = i + 1;
}

// ---------------- scatter-mean pooling: grid (NGRAPH, 6), 128 thr ----------------
__global__ __launch_bounds__(128) void k_pool(const float* __restrict__ nf,
                                              const int* __restrict__ gstart, const int* __restrict__ gend,
                                              float* __restrict__ gfeat) {
    int g = blockIdx.x, d = blockIdx.y * 128 + threadIdx.x;
    int s = gstart[g], e = gend[g];
    float a = 0.f;
    for (int n = s; n < e; ++n) a += nf[(size_t)n * DOUT + d];
    gfeat[g * DOUT + d] = a / fmaxf((float)(e - s), 1.f);
}

// ---------------- small MLP (M=64):  C = act(A[64][768] @ B[768][768] + bias) ----------------
template<int ACT>   // 0 none, 2 tanh
__global__ __launch_bounds__(256) void k_mlp64(const float* __restrict__ A, const float* __restrict__ B,
                                               const float* __restrict__ bias, float* __restrict__ C) {
    int idx = blockIdx.x * 256 + threadIdx.x;
    int m = idx / 768, n = idx % 768;
    const float* Ar = A + m * 768;
    float s = 0.f;
#pragma unroll 4
    for (int k = 0; k < 768; ++k) s = fmaf(Ar[k], B[(size_t)k * 768 + n], s);
    s += bias[n];
    if (ACT == 2) s = tanhf(s);
    C[idx] = s;
}

// ---------------- fused attention: scores -> softmax -> re + loss ----------------
// grid 256 blocks x 256 thr; block handles 32 rows; wave w owns rows w*8..w*8+7 (lane = slot).
__global__ __launch_bounds__(256) void k_attention(
    const float* __restrict__ nf, const float* __restrict__ mem,
    float* __restrict__ re, float* __restrict__ lossac) {
    __shared__ float4 Mlds[64][32];    // swizzled: slot c^(k&7)
    __shared__ float4 NFlds[32][32];
    __shared__ float Wlds[32][64];
    int tid = threadIdx.x, l = tid & 63, w = tid >> 6;
    int base = blockIdx.x * 32;
    const float4* nf4 = (const float4*)nf;
    const float4* m4p = (const float4*)mem;

    float s[8];
#pragma unroll
    for (int r = 0; r < 8; ++r) s[r] = 0.f;

    for (int dt = 0; dt < 6; ++dt) {
        __syncthreads();
#pragma unroll
        for (int i = 0; i < 8; ++i) {
            int si = tid + i * 256;
            int k = si >> 5, c = si & 31;
            Mlds[k][c ^ (k & 7)] = m4p[(size_t)k * 192 + dt * 32 + c];
        }
#pragma unroll
        for (int i = 0; i < 4; ++i) {
            int si = tid + i * 256;
            int r = si >> 5, c = si & 31;
            NFlds[r][c] = nf4[(size_t)(base + r) * 192 + dt * 32 + c];
        }
        __syncthreads();
        for (int c = 0; c < 32; ++c) {
            float4 mv = Mlds[l][c ^ (l & 7)];
#pragma unroll
            for (int r = 0; r < 8; ++r) {
                float4 xv = NFlds[w * 8 + r][c];
                s[r] += mv.x * xv.x + mv.y * xv.y + mv.z * xv.z + mv.w * xv.w;
            }
        }
    }
    // softmax over lanes (64 slots)
#pragma unroll
    for (int r = 0; r < 8; ++r) {
        float mx = s[r];
        for (int o = 32; o; o >>= 1) mx = fmaxf(mx, __shfl_xor(mx, o));
        float e = __expf(s[r] - mx);
        float sm = e;
        for (int o = 32; o; o >>= 1) sm += __shfl_xor(sm, o);
        Wlds[w * 8 + r][l] = e / sm;
    }
    float lp = 0.f;
    for (int dt = 0; dt < 6; ++dt) {
        __syncthreads();
#pragma unroll
        for (int i = 0; i < 8; ++i) {
            int si = tid + i * 256;
            int k = si >> 5, c = si & 31;
            Mlds[k][c ^ (k & 7)] = m4p[(size_t)k * 192 + dt * 32 + c];
        }
#pragma unroll
        for (int i = 0; i < 4; ++i) {
            int si = tid + i * 256;
            int r = si >> 5, c = si & 31;
            NFlds[r][c] = nf4[(size_t)(base + r) * 192 + dt * 32 + c];
        }
        __syncthreads();
#pragma unroll
        for (int r = 0; r < 8; ++r) {
            int rb = w * 8 + r;
            float a0 = 0.f, a1 = 0.f;
            for (int k = 0; k < 64; ++k) {
                float wk = Wlds[rb][k];
                float4 qv = Mlds[k][(l >> 1) ^ (k & 7)];
                float m0v = (l & 1) ? qv.z : qv.x;
                float m1v = (l & 1) ? qv.w : qv.y;
                a0 = fmaf(wk, m0v, a0);
                a1 = fmaf(wk, m1v, a1);
            }
            a0 *= (1.f / 64.f); a1 *= (1.f / 64.f);
            float4 xq = NFlds[rb][l >> 1];
            float x0 = (l & 1) ? xq.z : xq.x;
            float x1 = (l & 1) ? xq.w : xq.y;
            int d = dt * 128 + 2 * l;
            float2 st; st.x = a0; st.y = a1;
            *(float2*)(re + (size_t)(base + rb) * DOUT + d) = st;
            float d0 = x0 - a0, d1 = x1 - a1;
            lp += d0 * d0 + d1 * d1;
        }
    }
    for (int o = 32; o; o >>= 1) lp += __shfl_xor(lp, o);
    if (l == 0) atomicAdd(lossac, lp);
}

__global__ void k_loss_final(const float* __restrict__ acc, float* __restrict__ out, float invn) {
    if (threadIdx.x == 0 && blockIdx.x == 0) out[0] = acc[0] * invn;
}

// ---------------- launch ----------------
extern "C" void kernel_launch(void* const* d_in, const int* in_sizes, int n_in,
                              void* d_out, int out_size, void* d_ws, size_t ws_size,
                              hipStream_t stream) {
    const float* feature  = (const float*)d_in[0];
    const float* ppr      = (const float*)d_in[1];
    const float* edge_attr= (const float*)d_in[2];
    const float* Ws       = (const float*)d_in[3];
    const float* bs       = (const float*)d_in[4];
    const float* W1       = (const float*)d_in[5];
    const float* b1       = (const float*)d_in[6];
    const float* prelu_a  = (const float*)d_in[7];
    const float* W2       = (const float*)d_in[8];
    const float* b2       = (const float*)d_in[9];
    const float* Wp1      = (const float*)d_in[10];
    const float* bp1      = (const float*)d_in[11];
    const float* Wp2      = (const float*)d_in[12];
    const float* bp2      = (const float*)d_in[13];
    const float* memory   = (const float*)d_in[14];
    const int*   edge_index = (const int*)d_in[15];
    const int*   batch_ids  = (const int*)d_in[16];

    const int E = in_sizes[15] / 2;
    const int N = in_sizes[0] / DIN;
    const int* col = edge_index + E;

    char* ws = (char*)d_ws;
    ushort_t* Xhi  = (ushort_t*)(ws + OFF_XHI);
    ushort_t* Xlo  = (ushort_t*)(ws + OFF_XLO);
    ushort_t* Hhi  = (ushort_t*)(ws + OFF_HHI);
    ushort_t* Hlo  = (ushort_t*)(ws + OFF_HLO);
    float*    nf   = (float*)   (ws + OFF_NF);
    ushort_t* W1Thi= (ushort_t*)(ws + OFF_W1THI);
    ushort_t* W1Tlo= (ushort_t*)(ws + OFF_W1TLO);
    ushort_t* W2Thi= (ushort_t*)(ws + OFF_W2THI);
    ushort_t* W2Tlo= (ushort_t*)(ws + OFF_W2TLO);
    int*   bucket = (int*)(ws + OFF_BUCKET);
    int*   counts = (int*)(ws + OFF_COUNTS);
    int*   gstart = (int*)(ws + OFF_GSTART);
    int*   gend   = (int*)(ws + OFF_GEND);
    float* lossac = (float*)(ws + OFF_LOSS);
    float* gfeat  = (float*)(ws + OFF_GFEAT);
    float* t1     = (float*)(ws + OFF_T1);

    float* out_pooled = (float*)d_out;
    float* out_re     = (float*)d_out + NGRAPH * DOUT;
    float* out_loss   = (float*)d_out + NGRAPH * DOUT + (size_t)N * DOUT;

    (void)hipMemsetAsync(ws + ZERO_OFF, 0, ZERO_BYTES, stream);

    k_wsplit<<<dim3(768 / 32, 800 / 32), 256, 0, stream>>>(W1, W1Thi, W1Tlo, XDIM, DHID);
    k_wsplit<<<dim3(768 / 32, 768 / 32), 256, 0, stream>>>(W2, W2Thi, W2Tlo, DHID, DOUT);

    k_fill_bucket<<<1024, 256, 0, stream>>>(col, counts, bucket, E);
    k_aggregate<<<N, 192, 0, stream>>>(feature, edge_attr, ppr, Ws, bs, bucket, counts, Xhi, Xlo);

    // h = prelu(X @ W1 + b1)  -> planes
    k_gemm_mfma<1, 1><<<dim3(DHID / 128, N / 64), 256, 0, stream>>>(
        Xhi, Xlo, W1Thi, W1Tlo, b1, prelu_a, nullptr, Hhi, Hlo, N, DHID, XDIM);
    // nf = h @ W2 + b2 -> f32
    k_gemm_mfma<0, 0><<<dim3(DOUT / 128, N / 64), 256, 0, stream>>>(
        Hhi, Hlo, W2Thi, W2Tlo, b2, nullptr, nf, nullptr, nullptr, N, DOUT, DHID);

    k_boundaries<<<(N + 255) / 256, 256, 0, stream>>>(batch_ids, gstart, gend, N);
    k_pool<<<dim3(NGRAPH, 6), 128, 0, stream>>>(nf, gstart, gend, gfeat);

    k_mlp64<2><<<192, 256, 0, stream>>>(gfeat, Wp1, bp1, t1);
    k_mlp64<0><<<192, 256, 0, stream>>>(t1, Wp2, bp2, out_pooled);

    k_attention<<<N / 32, 256, 0, stream>>>(nf, memory, out_re, lossac);
    k_loss_final<<<1, 64, 0, stream>>>(lossac, out_loss, 1.f / (float)((size_t)N * DOUT));
}

// Round 4
// 588.125 us; speedup vs baseline: 2.0058x; 1.2154x over previous
//
#include <hip/hip_runtime.h>
#include <hip/hip_bf16.h>
#include <math.h>

typedef unsigned short ushort_t;
typedef short bf16x8 __attribute__((ext_vector_type(8)));
typedef float f32x4 __attribute__((ext_vector_type(4)));

#define NNODES   8192
#define DIN      768
#define DSTRUCT  32
#define XDIM     800
#define DHID     768
#define DOUT     768
#define MEMK     64
#define NGRAPH   64
#define BUCKET_CAP 128

// ---------------- workspace layout (bytes) ----------------
#define OFF_XHI     0u
#define OFF_XLO     (OFF_XHI  + 8192u*800u*2u)
#define OFF_HHI     (OFF_XLO  + 8192u*800u*2u)
#define OFF_HLO     (OFF_HHI  + 8192u*768u*2u)
#define OFF_NF      (OFF_HLO  + 8192u*768u*2u)
#define OFF_NFHI    (OFF_NF   + 8192u*768u*4u)
#define OFF_NFLO    (OFF_NFHI + 8192u*768u*2u)
#define OFF_W1THI   (OFF_NFLO + 8192u*768u*2u)
#define OFF_W1TLO   (OFF_W1THI + 768u*800u*2u)
#define OFF_W2THI   (OFF_W1TLO + 768u*800u*2u)
#define OFF_W2TLO   (OFF_W2THI + 768u*768u*2u)
#define OFF_MHI     (OFF_W2TLO + 768u*768u*2u)
#define OFF_MLO     (OFF_MHI  + 64u*768u*2u)
#define OFF_MTHI    (OFF_MLO  + 64u*768u*2u)
#define OFF_MTLO    (OFF_MTHI + 768u*64u*2u)
#define OFF_BUCKET  (OFF_MTLO + 768u*64u*2u)
#define OFF_COUNTS  (OFF_BUCKET + 8192u*BUCKET_CAP*4u)
#define OFF_GSTART  (OFF_COUNTS + 8192u*4u)
#define OFF_GEND    (OFF_GSTART + 256u)
#define OFF_LOSS    (OFF_GEND + 256u)
#define OFF_GFEAT   (OFF_LOSS + 256u)
#define OFF_T1      (OFF_GFEAT + 64u*768u*4u)
#define ZERO_OFF    OFF_COUNTS
#define ZERO_BYTES  (8192u*4u + 256u + 256u + 256u)

// ---------------- helpers ----------------
__device__ __forceinline__ ushort_t bf_rne(float f) {
    unsigned u = __float_as_uint(f);
    return (ushort_t)((u + 0x7FFFu + ((u >> 16) & 1u)) >> 16);
}
__device__ __forceinline__ void split_bf16(float f, ushort_t& hi, ushort_t& lo) {
    ushort_t h = bf_rne(f);
    float fh = __uint_as_float(((unsigned)h) << 16);
    hi = h;
    lo = bf_rne(f - fh);
}
__device__ __forceinline__ void gld16(const void* g, void* l) {
    __builtin_amdgcn_global_load_lds(
        (const __attribute__((address_space(1))) unsigned int*)g,
        (__attribute__((address_space(3))) unsigned int*)l, 16, 0, 0);
}

// ---------------- CSR build ----------------
__global__ void k_fill_bucket(const int* __restrict__ col, int* __restrict__ counts,
                              int* __restrict__ bucket, int E) {
    for (int e = blockIdx.x * blockDim.x + threadIdx.x; e < E; e += gridDim.x * blockDim.x) {
        int c = col[e];
        if ((unsigned)c < (unsigned)NNODES) {
            int p = atomicAdd(&counts[c], 1);
            if (p < BUCKET_CAP) bucket[c * BUCKET_CAP + p] = e;
        }
    }
}

// ---------------- aggregate edges -> X planes (bf16 hi/lo) ----------------
__global__ __launch_bounds__(192) void k_aggregate(
    const float* __restrict__ feature, const float* __restrict__ edge_attr,
    const float* __restrict__ ppr, const float* __restrict__ Ws, const float* __restrict__ bs,
    const int* __restrict__ bucket, const int* __restrict__ counts,
    ushort_t* __restrict__ Xhi, ushort_t* __restrict__ Xlo) {
    int n = blockIdx.x;
    int t = threadIdx.x;
    const float4* frow = (const float4*)(feature + (size_t)n * DIN);
    float4 acc = frow[t];
    int deg = min(counts[n], BUCKET_CAP);
    const int* bk = bucket + n * BUCKET_CAP;
    for (int j = 0; j < deg; ++j) {
        int e = bk[j];
        float4 v = ((const float4*)(edge_attr + (size_t)e * DIN))[t];
        acc.x += v.x; acc.y += v.y; acc.z += v.z; acc.w += v.w;
    }
    ushort4 h4, l4;
    split_bf16(acc.x, h4.x, l4.x); split_bf16(acc.y, h4.y, l4.y);
    split_bf16(acc.z, h4.z, l4.z); split_bf16(acc.w, h4.w, l4.w);
    *(ushort4*)(Xhi + (size_t)n * XDIM + t * 4) = h4;
    *(ushort4*)(Xlo + (size_t)n * XDIM + t * 4) = l4;
    if (t < DSTRUCT / 4) {
        float p = ppr[n];
        int k = t * 4;
        float4 s;
        s.x = fmaxf(p * Ws[k+0] + bs[k+0], 0.f);
        s.y = fmaxf(p * Ws[k+1] + bs[k+1], 0.f);
        s.z = fmaxf(p * Ws[k+2] + bs[k+2], 0.f);
        s.w = fmaxf(p * Ws[k+3] + bs[k+3], 0.f);
        ushort4 sh, sl;
        split_bf16(s.x, sh.x, sl.x); split_bf16(s.y, sh.y, sl.y);
        split_bf16(s.z, sh.z, sl.z); split_bf16(s.w, sh.w, sl.w);
        *(ushort4*)(Xhi + (size_t)n * XDIM + DIN + k) = sh;
        *(ushort4*)(Xlo + (size_t)n * XDIM + DIN + k) = sl;
    }
}

// ---------------- weight transpose + split:  W[K][N] f32 -> T_hi/lo[N][K] bf16 ----------------
__global__ __launch_bounds__(256) void k_wsplit(const float* __restrict__ W,
                                                ushort_t* __restrict__ Thi, ushort_t* __restrict__ Tlo,
                                                int K, int N) {
    __shared__ float tile[32][33];
    int n0 = blockIdx.x * 32, k0 = blockIdx.y * 32;
    int tx = threadIdx.x & 31, ty = threadIdx.x >> 5;
#pragma unroll
    for (int i = 0; i < 4; ++i) {
        int k = ty + i * 8;
        tile[k][tx] = W[(size_t)(k0 + k) * N + n0 + tx];
    }
    __syncthreads();
#pragma unroll
    for (int i = 0; i < 4; ++i) {
        int nn = ty + i * 8;
        float v = tile[tx][nn];
        ushort_t hi, lo; split_bf16(v, hi, lo);
        Thi[(size_t)(n0 + nn) * K + k0 + tx] = hi;
        Tlo[(size_t)(n0 + nn) * K + k0 + tx] = lo;
    }
}

// ---------------- elementwise split: memory [64][768] -> hi/lo planes ----------------
__global__ void k_msplit(const float* __restrict__ m, ushort_t* __restrict__ hi,
                         ushort_t* __restrict__ lo, int n) {
    int i = blockIdx.x * 256 + threadIdx.x;
    if (i >= n) return;
    ushort_t h, l; split_bf16(m[i], h, l);
    hi[i] = h; lo[i] = l;
}

// ---------------- split-bf16 MFMA GEMM ----------------
// C[M][N] = act(A@B^T + bias);  A planes [M][K], BT planes [N][K] (bf16 hi/lo)
// BM=64 BN=128 BK=32, 256 thr = 4 waves (2M x 2N), wave tile 32x64.
#define L_AHI 0
#define L_ALO 2048
#define L_BHI 4096
#define L_BLO 8192
#define L_BUF 12288

template<int ACT, int OUTMODE>   // ACT: 0 none, 1 prelu ; OUTMODE: 1 planes, 2 f32+planes
__global__ __launch_bounds__(256) void k_gemm_mfma(
    const ushort_t* __restrict__ Ahi, const ushort_t* __restrict__ Alo,
    const ushort_t* __restrict__ Bhi, const ushort_t* __restrict__ Blo,
    const float* __restrict__ bias, const float* __restrict__ act_p,
    float* __restrict__ Cf, ushort_t* __restrict__ Chi, ushort_t* __restrict__ Clo,
    int M, int N, int K) {
    __shared__ ushort_t lds[2 * L_BUF];
    int tid = threadIdx.x;
    int l = tid & 63, w = tid >> 6;

    int nbx = N / 128;
    int nwg = nbx * (M / 64);
    int bid = blockIdx.y * nbx + blockIdx.x;
    int q = nwg >> 3;
    int nb = (bid & 7) * q + (bid >> 3);
    int bx = nb % nbx, by = nb / nbx;
    int m0 = by * 64, n0 = bx * 128;

    int wm = w >> 1, wn = w & 1;

    f32x4 acc[2][4];
#pragma unroll
    for (int m = 0; m < 2; ++m)
#pragma unroll
        for (int n = 0; n < 4; ++n) acc[m][n] = (f32x4){0.f, 0.f, 0.f, 0.f};

    const ushort_t* agh = Ahi + (size_t)(m0 + l) * K + w * 8;
    const ushort_t* agl = Alo + (size_t)(m0 + l) * K + w * 8;
    int j0 = w, j1 = w + 4;
    const ushort_t* bgh0 = Bhi + (size_t)(n0 + (j0 & 1) * 64 + l) * K + (j0 >> 1) * 8;
    const ushort_t* bgl0 = Blo + (size_t)(n0 + (j0 & 1) * 64 + l) * K + (j0 >> 1) * 8;
    const ushort_t* bgh1 = Bhi + (size_t)(n0 + (j1 & 1) * 64 + l) * K + (j1 >> 1) * 8;
    const ushort_t* bgl1 = Blo + (size_t)(n0 + (j1 & 1) * 64 + l) * K + (j1 >> 1) * 8;

    int NT = K / 32;

    {
        ushort_t* b = lds;
        gld16(agh, b + L_AHI + w * 512);
        gld16(agl, b + L_ALO + w * 512);
        gld16(bgh0, b + L_BHI + j0 * 512);
        gld16(bgh1, b + L_BHI + j1 * 512);
        gld16(bgl0, b + L_BLO + j0 * 512);
        gld16(bgl1, b + L_BLO + j1 * 512);
    }

    int c0 = l >> 4;
    int arow = wm * 32 + (l & 15);
    int bcol = wn * 64 + (l & 15);

    for (int kt = 0; kt < NT; ++kt) {
        int cur = kt & 1;
        __syncthreads();
        if (kt + 1 < NT) {
            int ko = (kt + 1) * 32;
            ushort_t* b = lds + (cur ^ 1) * L_BUF;
            gld16(agh + ko, b + L_AHI + w * 512);
            gld16(agl + ko, b + L_ALO + w * 512);
            gld16(bgh0 + ko, b + L_BHI + j0 * 512);
            gld16(bgh1 + ko, b + L_BHI + j1 * 512);
            gld16(bgl0 + ko, b + L_BLO + j0 * 512);
            gld16(bgl1 + ko, b + L_BLO + j1 * 512);
        }
        const ushort_t* cb = lds + cur * L_BUF;
        bf16x8 ah[2], al[2], bh[4], bl[4];
#pragma unroll
        for (int m = 0; m < 2; ++m) {
            ah[m] = *(const bf16x8*)(cb + L_AHI + c0 * 512 + (arow + m * 16) * 8);
            al[m] = *(const bf16x8*)(cb + L_ALO + c0 * 512 + (arow + m * 16) * 8);
        }
#pragma unroll
        for (int n = 0; n < 4; ++n) {
            bh[n] = *(const bf16x8*)(cb + L_BHI + c0 * 1024 + (bcol + n * 16) * 8);
            bl[n] = *(const bf16x8*)(cb + L_BLO + c0 * 1024 + (bcol + n * 16) * 8);
        }
#pragma unroll
        for (int m = 0; m < 2; ++m)
#pragma unroll
            for (int n = 0; n < 4; ++n) {
                acc[m][n] = __builtin_amdgcn_mfma_f32_16x16x32_bf16(ah[m], bh[n], acc[m][n], 0, 0, 0);
                acc[m][n] = __builtin_amdgcn_mfma_f32_16x16x32_bf16(ah[m], bl[n], acc[m][n], 0, 0, 0);
                acc[m][n] = __builtin_amdgcn_mfma_f32_16x16x32_bf16(al[m], bh[n], acc[m][n], 0, 0, 0);
            }
    }

    float ap = (ACT == 1) ? *act_p : 0.f;
#pragma unroll
    for (int m = 0; m < 2; ++m)
#pragma unroll
        for (int n = 0; n < 4; ++n) {
            int col = n0 + wn * 64 + n * 16 + (l & 15);
            float bv = bias[col];
#pragma unroll
            for (int r = 0; r < 4; ++r) {
                int row = m0 + wm * 32 + m * 16 + (l >> 4) * 4 + r;
                float x = acc[m][n][r] + bv;
                if (ACT == 1) x = x > 0.f ? x : ap * x;
                ushort_t hi, lo; split_bf16(x, hi, lo);
                Chi[(size_t)row * N + col] = hi;
                Clo[(size_t)row * N + col] = lo;
                if (OUTMODE == 2) Cf[(size_t)row * N + col] = x;
            }
        }
}

// ---------------- graph boundaries ----------------
__global__ void k_boundaries(const int* __restrict__ batch, int* __restrict__ gstart,
                             int* __restrict__ gend, int n) {
    int i = blockIdx.x * blockDim.x + threadIdx.x;
    if (i >= n) return;
    int b = batch[i];
    if ((unsigned)b >= (unsigned)NGRAPH) return;
    if (i == 0 || batch[i - 1] != b) gstart[b] = i;
    if (i == n - 1 || batch[i + 1] != b) gend[b] = i + 1;
}

// ---------------- scatter-mean pooling ----------------
__global__ __launch_bounds__(128) void k_pool(const float* __restrict__ nf,
                                              const int* __restrict__ gstart, const int* __restrict__ gend,
                                              float* __restrict__ gfeat) {
    int g = blockIdx.x, d = blockIdx.y * 128 + threadIdx.x;
    int s = gstart[g], e = gend[g];
    float a = 0.f;
    for (int n = s; n < e; ++n) a += nf[(size_t)n * DOUT + d];
    gfeat[g * DOUT + d] = a / fmaxf((float)(e - s), 1.f);
}

// ---------------- small MLP (M=64) ----------------
template<int ACT>
__global__ __launch_bounds__(256) void k_mlp64(const float* __restrict__ A, const float* __restrict__ B,
                                               const float* __restrict__ bias, float* __restrict__ C) {
    int idx = blockIdx.x * 256 + threadIdx.x;
    int m = idx / 768, n = idx % 768;
    const float* Ar = A + m * 768;
    float s = 0.f;
#pragma unroll 4
    for (int k = 0; k < 768; ++k) s = fmaf(Ar[k], B[(size_t)k * 768 + n], s);
    s += bias[n];
    if (ACT == 2) s = tanhf(s);
    C[idx] = s;
}

// ---------------- fused MFMA attention: scores -> softmax -> PV + loss ----------------
// grid 256 blocks x 256 thr (4 waves). Block = 32 rows. Wave w: scores n-frag w (slots w*16..+15),
// PV col chunk w*192..+191.  NF planes staged once in LDS (96KB); memory/memT planes read from L2.
__global__ __launch_bounds__(256) void k_attn(
    const ushort_t* __restrict__ NFhi, const ushort_t* __restrict__ NFlo,
    const ushort_t* __restrict__ Mhi,  const ushort_t* __restrict__ Mlo,
    const ushort_t* __restrict__ MThi, const ushort_t* __restrict__ MTlo,
    const float* __restrict__ nf, float* __restrict__ re, float* __restrict__ lossac) {
    __shared__ ushort_t Ah[96 * 32 * 8];
    __shared__ ushort_t Al[96 * 32 * 8];
    __shared__ ushort_t Wp[2][32 * 64];
    __shared__ float xch[4][32];
    __shared__ float lred[4];
    int tid = threadIdx.x, l = tid & 63, w = tid >> 6;
    int g = l >> 4, li = l & 15;
    int base = blockIdx.x * 32;

    // stage NF rows [32][768] hi/lo, kchunk-major [96][32][8]
    for (int i = w * 12; i < w * 12 + 12; ++i) {
        int kc = i * 2 + (l >> 5), row = l & 31;
        gld16(NFhi + (size_t)(base + row) * 768 + kc * 8, Ah + i * 512);
        gld16(NFlo + (size_t)(base + row) * 768 + kc * 8, Al + i * 512);
    }
    __syncthreads();

    // ---- scores: rows 0..31 (2 m-frags) x slots w*16..+15
    f32x4 sacc[2];
    sacc[0] = (f32x4){0.f,0.f,0.f,0.f}; sacc[1] = (f32x4){0.f,0.f,0.f,0.f};
    int slot = w * 16 + li;
#pragma unroll 4
    for (int kt = 0; kt < 24; ++kt) {
        bf16x8 ah0 = *(const bf16x8*)(Ah + (kt * 4 + g) * 256 + li * 8);
        bf16x8 ah1 = *(const bf16x8*)(Ah + (kt * 4 + g) * 256 + (li + 16) * 8);
        bf16x8 al0 = *(const bf16x8*)(Al + (kt * 4 + g) * 256 + li * 8);
        bf16x8 al1 = *(const bf16x8*)(Al + (kt * 4 + g) * 256 + (li + 16) * 8);
        bf16x8 bh  = *(const bf16x8*)(Mhi + (size_t)slot * 768 + kt * 32 + g * 8);
        bf16x8 bl  = *(const bf16x8*)(Mlo + (size_t)slot * 768 + kt * 32 + g * 8);
        sacc[0] = __builtin_amdgcn_mfma_f32_16x16x32_bf16(ah0, bh, sacc[0], 0, 0, 0);
        sacc[0] = __builtin_amdgcn_mfma_f32_16x16x32_bf16(ah0, bl, sacc[0], 0, 0, 0);
        sacc[0] = __builtin_amdgcn_mfma_f32_16x16x32_bf16(al0, bh, sacc[0], 0, 0, 0);
        sacc[1] = __builtin_amdgcn_mfma_f32_16x16x32_bf16(ah1, bh, sacc[1], 0, 0, 0);
        sacc[1] = __builtin_amdgcn_mfma_f32_16x16x32_bf16(ah1, bl, sacc[1], 0, 0, 0);
        sacc[1] = __builtin_amdgcn_mfma_f32_16x16x32_bf16(al1, bh, sacc[1], 0, 0, 0);
    }

    // ---- softmax over 64 slots (16 in-wave + 4-wave LDS exchange)
    float mxv[8];
#pragma unroll
    for (int m = 0; m < 2; ++m)
#pragma unroll
        for (int r = 0; r < 4; ++r) {
            float v = sacc[m][r];
            v = fmaxf(v, __shfl_xor(v, 1)); v = fmaxf(v, __shfl_xor(v, 2));
            v = fmaxf(v, __shfl_xor(v, 4)); v = fmaxf(v, __shfl_xor(v, 8));
            mxv[m * 4 + r] = v;
        }
    if (li == 0) {
#pragma unroll
        for (int m = 0; m < 2; ++m)
#pragma unroll
            for (int r = 0; r < 4; ++r) xch[w][m * 16 + g * 4 + r] = mxv[m * 4 + r];
    }
    __syncthreads();
    float ev[8], sv[8];
#pragma unroll
    for (int m = 0; m < 2; ++m)
#pragma unroll
        for (int r = 0; r < 4; ++r) {
            int row = m * 16 + g * 4 + r;
            float mx = fmaxf(fmaxf(xch[0][row], xch[1][row]), fmaxf(xch[2][row], xch[3][row]));
            float e = __expf(sacc[m][r] - mx);
            ev[m * 4 + r] = e;
            float s = e;
            s += __shfl_xor(s, 1); s += __shfl_xor(s, 2);
            s += __shfl_xor(s, 4); s += __shfl_xor(s, 8);
            sv[m * 4 + r] = s;
        }
    __syncthreads();
    if (li == 0) {
#pragma unroll
        for (int m = 0; m < 2; ++m)
#pragma unroll
            for (int r = 0; r < 4; ++r) xch[w][m * 16 + g * 4 + r] = sv[m * 4 + r];
    }
    __syncthreads();
#pragma unroll
    for (int m = 0; m < 2; ++m)
#pragma unroll
        for (int r = 0; r < 4; ++r) {
            int row = m * 16 + g * 4 + r;
            float tot = xch[0][row] + xch[1][row] + xch[2][row] + xch[3][row];
            float wv = ev[m * 4 + r] / tot;
            ushort_t hi, lo; split_bf16(wv, hi, lo);
            int idx = row * 64 + (slot ^ ((row & 7) << 3));
            Wp[0][idx] = hi; Wp[1][idx] = lo;
        }
    __syncthreads();

    // ---- PV: re[32][768], A = Wp planes, B = MT planes (global/L2)
    bf16x8 wah[2][2], wal[2][2];
#pragma unroll
    for (int m = 0; m < 2; ++m)
#pragma unroll
        for (int kt2 = 0; kt2 < 2; ++kt2) {
            int row = m * 16 + li;
            int k8 = kt2 * 4 + g;
            int idx = row * 64 + ((k8 * 8) ^ ((row & 7) << 3));
            wah[m][kt2] = *(const bf16x8*)&Wp[0][idx];
            wal[m][kt2] = *(const bf16x8*)&Wp[1][idx];
        }
    float lp = 0.f;
#pragma unroll 2
    for (int nfi = 0; nfi < 12; ++nfi) {
        int col = w * 192 + nfi * 16 + li;
        f32x4 pacc[2];
        pacc[0] = (f32x4){0.f,0.f,0.f,0.f}; pacc[1] = (f32x4){0.f,0.f,0.f,0.f};
#pragma unroll
        for (int kt2 = 0; kt2 < 2; ++kt2) {
            bf16x8 bh = *(const bf16x8*)(MThi + (size_t)col * 64 + kt2 * 32 + g * 8);
            bf16x8 bl = *(const bf16x8*)(MTlo + (size_t)col * 64 + kt2 * 32 + g * 8);
#pragma unroll
            for (int m = 0; m < 2; ++m) {
                pacc[m] = __builtin_amdgcn_mfma_f32_16x16x32_bf16(wah[m][kt2], bh, pacc[m], 0, 0, 0);
                pacc[m] = __builtin_amdgcn_mfma_f32_16x16x32_bf16(wah[m][kt2], bl, pacc[m], 0, 0, 0);
                pacc[m] = __builtin_amdgcn_mfma_f32_16x16x32_bf16(wal[m][kt2], bh, pacc[m], 0, 0, 0);
            }
        }
#pragma unroll
        for (int m = 0; m < 2; ++m)
#pragma unroll
            for (int r = 0; r < 4; ++r) {
                int row = base + m * 16 + g * 4 + r;
                float v = pacc[m][r] * (1.f / 64.f);
                float x = nf[(size_t)row * 768 + col];
                re[(size_t)row * 768 + col] = v;
                float d = x - v;
                lp = fmaf(d, d, lp);
            }
    }
    for (int o = 32; o; o >>= 1) lp += __shfl_xor(lp, o);
    if (l == 0) lred[w] = lp;
    __syncthreads();
    if (tid == 0) atomicAdd(lossac, lred[0] + lred[1] + lred[2] + lred[3]);
}

__global__ void k_loss_final(const float* __restrict__ acc, float* __restrict__ out, float invn) {
    if (threadIdx.x == 0 && blockIdx.x == 0) out[0] = acc[0] * invn;
}

// ---------------- launch ----------------
extern "C" void kernel_launch(void* const* d_in, const int* in_sizes, int n_in,
                              void* d_out, int out_size, void* d_ws, size_t ws_size,
                              hipStream_t stream) {
    const float* feature  = (const float*)d_in[0];
    const float* ppr      = (const float*)d_in[1];
    const float* edge_attr= (const float*)d_in[2];
    const float* Ws       = (const float*)d_in[3];
    const float* bs       = (const float*)d_in[4];
    const float* W1       = (const float*)d_in[5];
    const float* b1       = (const float*)d_in[6];
    const float* prelu_a  = (const float*)d_in[7];
    const float* W2       = (const float*)d_in[8];
    const float* b2       = (const float*)d_in[9];
    const float* Wp1      = (const float*)d_in[10];
    const float* bp1      = (const float*)d_in[11];
    const float* Wp2      = (const float*)d_in[12];
    const float* bp2      = (const float*)d_in[13];
    const float* memory   = (const float*)d_in[14];
    const int*   edge_index = (const int*)d_in[15];
    const int*   batch_ids  = (const int*)d_in[16];

    const int E = in_sizes[15] / 2;
    const int N = in_sizes[0] / DIN;
    const int* col = edge_index + E;

    char* ws = (char*)d_ws;
    ushort_t* Xhi  = (ushort_t*)(ws + OFF_XHI);
    ushort_t* Xlo  = (ushort_t*)(ws + OFF_XLO);
    ushort_t* Hhi  = (ushort_t*)(ws + OFF_HHI);
    ushort_t* Hlo  = (ushort_t*)(ws + OFF_HLO);
    float*    nf   = (float*)   (ws + OFF_NF);
    ushort_t* NFhi = (ushort_t*)(ws + OFF_NFHI);
    ushort_t* NFlo = (ushort_t*)(ws + OFF_NFLO);
    ushort_t* W1Thi= (ushort_t*)(ws + OFF_W1THI);
    ushort_t* W1Tlo= (ushort_t*)(ws + OFF_W1TLO);
    ushort_t* W2Thi= (ushort_t*)(ws + OFF_W2THI);
    ushort_t* W2Tlo= (ushort_t*)(ws + OFF_W2TLO);
    ushort_t* Mhi  = (ushort_t*)(ws + OFF_MHI);
    ushort_t* Mlo  = (ushort_t*)(ws + OFF_MLO);
    ushort_t* MThi = (ushort_t*)(ws + OFF_MTHI);
    ushort_t* MTlo = (ushort_t*)(ws + OFF_MTLO);
    int*   bucket = (int*)(ws + OFF_BUCKET);
    int*   counts = (int*)(ws + OFF_COUNTS);
    int*   gstart = (int*)(ws + OFF_GSTART);
    int*   gend   = (int*)(ws + OFF_GEND);
    float* lossac = (float*)(ws + OFF_LOSS);
    float* gfeat  = (float*)(ws + OFF_GFEAT);
    float* t1     = (float*)(ws + OFF_T1);

    float* out_pooled = (float*)d_out;
    float* out_re     = (float*)d_out + NGRAPH * DOUT;
    float* out_loss   = (float*)d_out + NGRAPH * DOUT + (size_t)N * DOUT;

    (void)hipMemsetAsync(ws + ZERO_OFF, 0, ZERO_BYTES, stream);

    k_wsplit<<<dim3(768 / 32, 800 / 32), 256, 0, stream>>>(W1, W1Thi, W1Tlo, XDIM, DHID);
    k_wsplit<<<dim3(768 / 32, 768 / 32), 256, 0, stream>>>(W2, W2Thi, W2Tlo, DHID, DOUT);
    k_wsplit<<<dim3(768 / 32, 64 / 32), 256, 0, stream>>>(memory, MThi, MTlo, MEMK, DOUT);
    k_msplit<<<(MEMK * 768 + 255) / 256, 256, 0, stream>>>(memory, Mhi, Mlo, MEMK * 768);

    k_fill_bucket<<<1024, 256, 0, stream>>>(col, counts, bucket, E);
    k_aggregate<<<N, 192, 0, stream>>>(feature, edge_attr, ppr, Ws, bs, bucket, counts, Xhi, Xlo);

    k_gemm_mfma<1, 1><<<dim3(DHID / 128, N / 64), 256, 0, stream>>>(
        Xhi, Xlo, W1Thi, W1Tlo, b1, prelu_a, nullptr, Hhi, Hlo, N, DHID, XDIM);
    k_gemm_mfma<0, 2><<<dim3(DOUT / 128, N / 64), 256, 0, stream>>>(
        Hhi, Hlo, W2Thi, W2Tlo, b2, nullptr, nf, NFhi, NFlo, N, DOUT, DHID);

    k_boundaries<<<(N + 255) / 256, 256, 0, stream>>>(batch_ids, gstart, gend, N);
    k_pool<<<dim3(NGRAPH, 6), 128, 0, stream>>>(nf, gstart, gend, gfeat);

    k_mlp64<2><<<192, 256, 0, stream>>>(gfeat, Wp1, bp1, t1);
    k_mlp64<0><<<192, 256, 0, stream>>>(t1, Wp2, bp2, out_pooled);

    k_attn<<<N / 32, 256, 0, stream>>>(NFhi, NFlo, Mhi, Mlo, MThi, MTlo, nf, out_re, lossac);
    k_loss_final<<<1, 64, 0, stream>>>(lossac, out_loss, 1.f / (float)((size_t)N * DOUT));
}

// Round 5
// 414.419 us; speedup vs baseline: 2.8466x; 1.4192x over previous
//
#include <hip/hip_runtime.h>
#include <hip/hip_bf16.h>
#include <math.h>

typedef unsigned short ushort_t;
typedef short bf16x8 __attribute__((ext_vector_type(8)));
typedef float f32x4 __attribute__((ext_vector_type(4)));

#define NNODES   8192
#define DIN      768
#define DSTRUCT  32
#define XDIM     800
#define DHID     768
#define DOUT     768
#define MEMK     64
#define NGRAPH   64
#define BUCKET_CAP 128

// ---------------- workspace layout (bytes) ----------------
#define OFF_XHI     0u
#define OFF_XLO     (OFF_XHI  + 8192u*800u*2u)
#define OFF_HHI     (OFF_XLO  + 8192u*800u*2u)
#define OFF_HLO     (OFF_HHI  + 8192u*768u*2u)
#define OFF_NF      (OFF_HLO  + 8192u*768u*2u)
#define OFF_NFHI    (OFF_NF   + 8192u*768u*4u)
#define OFF_NFLO    (OFF_NFHI + 8192u*768u*2u)
#define OFF_W1THI   (OFF_NFLO + 8192u*768u*2u)
#define OFF_W1TLO   (OFF_W1THI + 768u*800u*2u)
#define OFF_W2THI   (OFF_W1TLO + 768u*800u*2u)
#define OFF_W2TLO   (OFF_W2THI + 768u*768u*2u)
#define OFF_MHI     (OFF_W2TLO + 768u*768u*2u)
#define OFF_MLO     (OFF_MHI  + 64u*768u*2u)
#define OFF_MTHI    (OFF_MLO  + 64u*768u*2u)
#define OFF_MTLO    (OFF_MTHI + 768u*64u*2u)
#define OFF_BUCKET  (OFF_MTLO + 768u*64u*2u)
#define OFF_COUNTS  (OFF_BUCKET + 8192u*BUCKET_CAP*4u)
#define OFF_GSTART  (OFF_COUNTS + 8192u*4u)
#define OFF_GEND    (OFF_GSTART + 256u)
#define OFF_LOSS    (OFF_GEND + 256u)
#define OFF_GFEAT   (OFF_LOSS + 256u)          // gfeatT [768][64] f32
#define OFF_T1      (OFF_GFEAT + 768u*64u*4u)  // t1T [768][64] f32
#define ZERO_OFF    OFF_COUNTS
#define ZERO_BYTES  (8192u*4u + 256u + 256u + 256u)

// ---------------- helpers ----------------
__device__ __forceinline__ ushort_t bf_rne(float f) {
    unsigned u = __float_as_uint(f);
    return (ushort_t)((u + 0x7FFFu + ((u >> 16) & 1u)) >> 16);
}
__device__ __forceinline__ void split_bf16(float f, ushort_t& hi, ushort_t& lo) {
    ushort_t h = bf_rne(f);
    float fh = __uint_as_float(((unsigned)h) << 16);
    hi = h;
    lo = bf_rne(f - fh);
}
__device__ __forceinline__ void gld16(const void* g, void* l) {
    __builtin_amdgcn_global_load_lds(
        (const __attribute__((address_space(1))) unsigned int*)g,
        (__attribute__((address_space(3))) unsigned int*)l, 16, 0, 0);
}

// ---------------- CSR build ----------------
__global__ void k_fill_bucket(const int* __restrict__ col, int* __restrict__ counts,
                              int* __restrict__ bucket, int E) {
    for (int e = blockIdx.x * blockDim.x + threadIdx.x; e < E; e += gridDim.x * blockDim.x) {
        int c = col[e];
        if ((unsigned)c < (unsigned)NNODES) {
            int p = atomicAdd(&counts[c], 1);
            if (p < BUCKET_CAP) bucket[c * BUCKET_CAP + p] = e;
        }
    }
}

// ---------------- aggregate edges -> X planes (bf16 hi/lo) ----------------
__global__ __launch_bounds__(192) void k_aggregate(
    const float* __restrict__ feature, const float* __restrict__ edge_attr,
    const float* __restrict__ ppr, const float* __restrict__ Ws, const float* __restrict__ bs,
    const int* __restrict__ bucket, const int* __restrict__ counts,
    ushort_t* __restrict__ Xhi, ushort_t* __restrict__ Xlo) {
    int n = blockIdx.x;
    int t = threadIdx.x;
    const float4* frow = (const float4*)(feature + (size_t)n * DIN);
    float4 acc = frow[t];
    int deg = min(counts[n], BUCKET_CAP);
    const int* bk = bucket + n * BUCKET_CAP;
    for (int j = 0; j < deg; ++j) {
        int e = bk[j];
        float4 v = ((const float4*)(edge_attr + (size_t)e * DIN))[t];
        acc.x += v.x; acc.y += v.y; acc.z += v.z; acc.w += v.w;
    }
    ushort4 h4, l4;
    split_bf16(acc.x, h4.x, l4.x); split_bf16(acc.y, h4.y, l4.y);
    split_bf16(acc.z, h4.z, l4.z); split_bf16(acc.w, h4.w, l4.w);
    *(ushort4*)(Xhi + (size_t)n * XDIM + t * 4) = h4;
    *(ushort4*)(Xlo + (size_t)n * XDIM + t * 4) = l4;
    if (t < DSTRUCT / 4) {
        float p = ppr[n];
        int k = t * 4;
        float4 s;
        s.x = fmaxf(p * Ws[k+0] + bs[k+0], 0.f);
        s.y = fmaxf(p * Ws[k+1] + bs[k+1], 0.f);
        s.z = fmaxf(p * Ws[k+2] + bs[k+2], 0.f);
        s.w = fmaxf(p * Ws[k+3] + bs[k+3], 0.f);
        ushort4 sh, sl;
        split_bf16(s.x, sh.x, sl.x); split_bf16(s.y, sh.y, sl.y);
        split_bf16(s.z, sh.z, sl.z); split_bf16(s.w, sh.w, sl.w);
        *(ushort4*)(Xhi + (size_t)n * XDIM + DIN + k) = sh;
        *(ushort4*)(Xlo + (size_t)n * XDIM + DIN + k) = sl;
    }
}

// ---------------- weight transpose + split:  W[K][N] f32 -> T_hi/lo[N][K] bf16 ----------------
__global__ __launch_bounds__(256) void k_wsplit(const float* __restrict__ W,
                                                ushort_t* __restrict__ Thi, ushort_t* __restrict__ Tlo,
                                                int K, int N) {
    __shared__ float tile[32][33];
    int n0 = blockIdx.x * 32, k0 = blockIdx.y * 32;
    int tx = threadIdx.x & 31, ty = threadIdx.x >> 5;
#pragma unroll
    for (int i = 0; i < 4; ++i) {
        int k = ty + i * 8;
        tile[k][tx] = W[(size_t)(k0 + k) * N + n0 + tx];
    }
    __syncthreads();
#pragma unroll
    for (int i = 0; i < 4; ++i) {
        int nn = ty + i * 8;
        float v = tile[tx][nn];
        ushort_t hi, lo; split_bf16(v, hi, lo);
        Thi[(size_t)(n0 + nn) * K + k0 + tx] = hi;
        Tlo[(size_t)(n0 + nn) * K + k0 + tx] = lo;
    }
}

// ---------------- elementwise split: memory [64][768] -> hi/lo planes ----------------
__global__ void k_msplit(const float* __restrict__ m, ushort_t* __restrict__ hi,
                         ushort_t* __restrict__ lo, int n) {
    int i = blockIdx.x * 256 + threadIdx.x;
    if (i >= n) return;
    ushort_t h, l; split_bf16(m[i], h, l);
    hi[i] = h; lo[i] = l;
}

// ---------------- split-bf16 MFMA GEMM ----------------
// C[M][N] = act(A@B^T + bias);  A planes [M][K], BT planes [N][K] (bf16 hi/lo)
// BM=64 BN=128 BK=32, 256 thr = 4 waves (2M x 2N), wave tile 32x64.
// LDS per buf (ushort offsets): Ahi[64][32] @0, Alo @2048, Bhi[128][32] @4096, Blo @8192.
// Staging is 64B-granular: 4 lanes cover one row's 32 k-elems (row-major tiles).
#define L_ALO 2048
#define L_BHI 4096
#define L_BLO 8192
#define L_BUF 12288

template<int ACT, int OUTMODE>   // ACT: 0 none, 1 prelu ; OUTMODE: 1 planes, 2 f32+planes
__global__ __launch_bounds__(256) void k_gemm_mfma(
    const ushort_t* __restrict__ Ahi, const ushort_t* __restrict__ Alo,
    const ushort_t* __restrict__ Bhi, const ushort_t* __restrict__ Blo,
    const float* __restrict__ bias, const float* __restrict__ act_p,
    float* __restrict__ Cf, ushort_t* __restrict__ Chi, ushort_t* __restrict__ Clo,
    int M, int N, int K) {
    __shared__ ushort_t lds[2 * L_BUF];
    int tid = threadIdx.x;
    int l = tid & 63, w = tid >> 6;

    int nbx = N / 128;
    int nwg = nbx * (M / 64);
    int bid = blockIdx.y * nbx + blockIdx.x;
    int q = nwg >> 3;
    int nb = (bid & 7) * q + (bid >> 3);
    int bx = nb % nbx, by = nb / nbx;
    int m0 = by * 64, n0 = bx * 128;

    int wm = w >> 1, wn = w & 1;

    f32x4 acc[2][4];
#pragma unroll
    for (int m = 0; m < 2; ++m)
#pragma unroll
        for (int n = 0; n < 4; ++n) acc[m][n] = (f32x4){0.f, 0.f, 0.f, 0.f};

    // staging: lane l covers row (w*16 + l/4), 16B chunk (l&3) of the 64B row
    int srow = w * 16 + (l >> 2);
    int sc   = (l & 3) * 8;
    const ushort_t* agh  = Ahi + (size_t)(m0 + srow) * K + sc;
    const ushort_t* agl  = Alo + (size_t)(m0 + srow) * K + sc;
    const ushort_t* bgh0 = Bhi + (size_t)(n0 + srow) * K + sc;
    const ushort_t* bgh1 = Bhi + (size_t)(n0 + 64 + srow) * K + sc;
    const ushort_t* bgl0 = Blo + (size_t)(n0 + srow) * K + sc;
    const ushort_t* bgl1 = Blo + (size_t)(n0 + 64 + srow) * K + sc;

    int NT = K / 32;

    {
        ushort_t* b = lds;
        gld16(agh,  b + w * 512);
        gld16(agl,  b + L_ALO + w * 512);
        gld16(bgh0, b + L_BHI + w * 512);
        gld16(bgh1, b + L_BHI + 2048 + w * 512);
        gld16(bgl0, b + L_BLO + w * 512);
        gld16(bgl1, b + L_BLO + 2048 + w * 512);
    }

    int c0 = l >> 4;            // kchunk 0..3
    int arow = wm * 32 + (l & 15);
    int bcol = wn * 64 + (l & 15);

    for (int kt = 0; kt < NT; ++kt) {
        int cur = kt & 1;
        __syncthreads();
        if (kt + 1 < NT) {
            int ko = (kt + 1) * 32;
            ushort_t* b = lds + (cur ^ 1) * L_BUF;
            gld16(agh + ko,  b + w * 512);
            gld16(agl + ko,  b + L_ALO + w * 512);
            gld16(bgh0 + ko, b + L_BHI + w * 512);
            gld16(bgh1 + ko, b + L_BHI + 2048 + w * 512);
            gld16(bgl0 + ko, b + L_BLO + w * 512);
            gld16(bgl1 + ko, b + L_BLO + 2048 + w * 512);
        }
        const ushort_t* cb = lds + cur * L_BUF;
        bf16x8 ah[2], al[2], bh[4], bl[4];
#pragma unroll
        for (int m = 0; m < 2; ++m) {
            ah[m] = *(const bf16x8*)(cb + (arow + m * 16) * 32 + c0 * 8);
            al[m] = *(const bf16x8*)(cb + L_ALO + (arow + m * 16) * 32 + c0 * 8);
        }
#pragma unroll
        for (int n = 0; n < 4; ++n) {
            bh[n] = *(const bf16x8*)(cb + L_BHI + (bcol + n * 16) * 32 + c0 * 8);
            bl[n] = *(const bf16x8*)(cb + L_BLO + (bcol + n * 16) * 32 + c0 * 8);
        }
#pragma unroll
        for (int m = 0; m < 2; ++m)
#pragma unroll
            for (int n = 0; n < 4; ++n) {
                acc[m][n] = __builtin_amdgcn_mfma_f32_16x16x32_bf16(ah[m], bh[n], acc[m][n], 0, 0, 0);
                acc[m][n] = __builtin_amdgcn_mfma_f32_16x16x32_bf16(ah[m], bl[n], acc[m][n], 0, 0, 0);
                acc[m][n] = __builtin_amdgcn_mfma_f32_16x16x32_bf16(al[m], bh[n], acc[m][n], 0, 0, 0);
            }
    }

    float ap = (ACT == 1) ? *act_p : 0.f;
#pragma unroll
    for (int m = 0; m < 2; ++m)
#pragma unroll
        for (int n = 0; n < 4; ++n) {
            int col = n0 + wn * 64 + n * 16 + (l & 15);
            float bv = bias[col];
#pragma unroll
            for (int r = 0; r < 4; ++r) {
                int row = m0 + wm * 32 + m * 16 + (l >> 4) * 4 + r;
                float x = acc[m][n][r] + bv;
                if (ACT == 1) x = x > 0.f ? x : ap * x;
                ushort_t hi, lo; split_bf16(x, hi, lo);
                Chi[(size_t)row * N + col] = hi;
                Clo[(size_t)row * N + col] = lo;
                if (OUTMODE == 2) Cf[(size_t)row * N + col] = x;
            }
        }
}

// ---------------- graph boundaries ----------------
__global__ void k_boundaries(const int* __restrict__ batch, int* __restrict__ gstart,
                             int* __restrict__ gend, int n) {
    int i = blockIdx.x * blockDim.x + threadIdx.x;
    if (i >= n) return;
    int b = batch[i];
    if ((unsigned)b >= (unsigned)NGRAPH) return;
    if (i == 0 || batch[i - 1] != b) gstart[b] = i;
    if (i == n - 1 || batch[i + 1] != b) gend[b] = i + 1;
}

// ---------------- scatter-mean pooling -> gfeatT [768][64] ----------------
__global__ __launch_bounds__(128) void k_pool(const float* __restrict__ nf,
                                              const int* __restrict__ gstart, const int* __restrict__ gend,
                                              float* __restrict__ gfeatT) {
    int g = blockIdx.x, d = blockIdx.y * 128 + threadIdx.x;
    int s = gstart[g], e = gend[g];
    float a = 0.f;
    for (int n = s; n < e; ++n) a += nf[(size_t)n * DOUT + d];
    gfeatT[(size_t)d * 64 + g] = a / fmaxf((float)(e - s), 1.f);
}

// ---------------- pooled MLP, transpose-fed: out[:,n] = act(A_T^T[:,k] dot B[:,n]) ----------------
// grid 768 blocks (one per col n), 256 thr = 4 waves; wave q does k in [q*192, q*192+192); lane = m.
template<int ACT>   // 2: tanh, write OutT[n][m] ; 0: none, write OutR[m][n]
__global__ __launch_bounds__(256) void k_mlp_t(const float* __restrict__ AT, const float* __restrict__ B,
                                               const float* __restrict__ bias,
                                               float* __restrict__ OutT, float* __restrict__ OutR) {
    __shared__ float red[4][64];
    int n = blockIdx.x;
    int l = threadIdx.x & 63, qw = threadIdx.x >> 6;
    float s = 0.f;
    const float* a = AT + l;
    const float* b = B + n;
#pragma unroll 8
    for (int k = qw * 192; k < qw * 192 + 192; ++k)
        s = fmaf(a[k * 64], b[k * 768], s);
    red[qw][l] = s;
    __syncthreads();
    if (threadIdx.x < 64) {
        float v = red[0][l] + red[1][l] + red[2][l] + red[3][l] + bias[n];
        if (ACT == 2) { v = tanhf(v); OutT[n * 64 + l] = v; }
        else OutR[(size_t)l * 768 + n] = v;
    }
}

// ---------------- fused MFMA attention: scores -> softmax -> PV + loss ----------------
__global__ __launch_bounds__(256) void k_attn(
    const ushort_t* __restrict__ NFhi, const ushort_t* __restrict__ NFlo,
    const ushort_t* __restrict__ Mhi,  const ushort_t* __restrict__ Mlo,
    const ushort_t* __restrict__ MThi, const ushort_t* __restrict__ MTlo,
    const float* __restrict__ nf, float* __restrict__ re, float* __restrict__ lossac) {
    __shared__ ushort_t Ah[96 * 32 * 8];
    __shared__ ushort_t Al[96 * 32 * 8];
    __shared__ ushort_t Wp[2][32 * 64];
    __shared__ float xch[4][32];
    __shared__ float lred[4];
    int tid = threadIdx.x, l = tid & 63, w = tid >> 6;
    int g = l >> 4, li = l & 15;
    int base = blockIdx.x * 32;

    for (int i = w * 12; i < w * 12 + 12; ++i) {
        int kc = i * 2 + (l >> 5), row = l & 31;
        gld16(NFhi + (size_t)(base + row) * 768 + kc * 8, Ah + i * 512);
        gld16(NFlo + (size_t)(base + row) * 768 + kc * 8, Al + i * 512);
    }
    __syncthreads();

    f32x4 sacc[2];
    sacc[0] = (f32x4){0.f,0.f,0.f,0.f}; sacc[1] = (f32x4){0.f,0.f,0.f,0.f};
    int slot = w * 16 + li;
#pragma unroll 4
    for (int kt = 0; kt < 24; ++kt) {
        bf16x8 ah0 = *(const bf16x8*)(Ah + (kt * 4 + g) * 256 + li * 8);
        bf16x8 ah1 = *(const bf16x8*)(Ah + (kt * 4 + g) * 256 + (li + 16) * 8);
        bf16x8 al0 = *(const bf16x8*)(Al + (kt * 4 + g) * 256 + li * 8);
        bf16x8 al1 = *(const bf16x8*)(Al + (kt * 4 + g) * 256 + (li + 16) * 8);
        bf16x8 bh  = *(const bf16x8*)(Mhi + (size_t)slot * 768 + kt * 32 + g * 8);
        bf16x8 bl  = *(const bf16x8*)(Mlo + (size_t)slot * 768 + kt * 32 + g * 8);
        sacc[0] = __builtin_amdgcn_mfma_f32_16x16x32_bf16(ah0, bh, sacc[0], 0, 0, 0);
        sacc[0] = __builtin_amdgcn_mfma_f32_16x16x32_bf16(ah0, bl, sacc[0], 0, 0, 0);
        sacc[0] = __builtin_amdgcn_mfma_f32_16x16x32_bf16(al0, bh, sacc[0], 0, 0, 0);
        sacc[1] = __builtin_amdgcn_mfma_f32_16x16x32_bf16(ah1, bh, sacc[1], 0, 0, 0);
        sacc[1] = __builtin_amdgcn_mfma_f32_16x16x32_bf16(ah1, bl, sacc[1], 0, 0, 0);
        sacc[1] = __builtin_amdgcn_mfma_f32_16x16x32_bf16(al1, bh, sacc[1], 0, 0, 0);
    }

    float mxv[8];
#pragma unroll
    for (int m = 0; m < 2; ++m)
#pragma unroll
        for (int r = 0; r < 4; ++r) {
            float v = sacc[m][r];
            v = fmaxf(v, __shfl_xor(v, 1)); v = fmaxf(v, __shfl_xor(v, 2));
            v = fmaxf(v, __shfl_xor(v, 4)); v = fmaxf(v, __shfl_xor(v, 8));
            mxv[m * 4 + r] = v;
        }
    if (li == 0) {
#pragma unroll
        for (int m = 0; m < 2; ++m)
#pragma unroll
            for (int r = 0; r < 4; ++r) xch[w][m * 16 + g * 4 + r] = mxv[m * 4 + r];
    }
    __syncthreads();
    float ev[8], sv[8];
#pragma unroll
    for (int m = 0; m < 2; ++m)
#pragma unroll
        for (int r = 0; r < 4; ++r) {
            int row = m * 16 + g * 4 + r;
            float mx = fmaxf(fmaxf(xch[0][row], xch[1][row]), fmaxf(xch[2][row], xch[3][row]));
            float e = __expf(sacc[m][r] - mx);
            ev[m * 4 + r] = e;
            float s = e;
            s += __shfl_xor(s, 1); s += __shfl_xor(s, 2);
            s += __shfl_xor(s, 4); s += __shfl_xor(s, 8);
            sv[m * 4 + r] = s;
        }
    __syncthreads();
    if (li == 0) {
#pragma unroll
        for (int m = 0; m < 2; ++m)
#pragma unroll
            for (int r = 0; r < 4; ++r) xch[w][m * 16 + g * 4 + r] = sv[m * 4 + r];
    }
    __syncthreads();
#pragma unroll
    for (int m = 0; m < 2; ++m)
#pragma unroll
        for (int r = 0; r < 4; ++r) {
            int row = m * 16 + g * 4 + r;
            float tot = xch[0][row] + xch[1][row] + xch[2][row] + xch[3][row];
            float wv = ev[m * 4 + r] / tot;
            ushort_t hi, lo; split_bf16(wv, hi, lo);
            int idx = row * 64 + (slot ^ ((row & 7) << 3));
            Wp[0][idx] = hi; Wp[1][idx] = lo;
        }
    __syncthreads();

    bf16x8 wah[2][2], wal[2][2];
#pragma unroll
    for (int m = 0; m < 2; ++m)
#pragma unroll
        for (int kt2 = 0; kt2 < 2; ++kt2) {
            int row = m * 16 + li;
            int k8 = kt2 * 4 + g;
            int idx = row * 64 + ((k8 * 8) ^ ((row & 7) << 3));
            wah[m][kt2] = *(const bf16x8*)&Wp[0][idx];
            wal[m][kt2] = *(const bf16x8*)&Wp[1][idx];
        }
    float lp = 0.f;
#pragma unroll 2
    for (int nfi = 0; nfi < 12; ++nfi) {
        int col = w * 192 + nfi * 16 + li;
        f32x4 pacc[2];
        pacc[0] = (f32x4){0.f,0.f,0.f,0.f}; pacc[1] = (f32x4){0.f,0.f,0.f,0.f};
#pragma unroll
        for (int kt2 = 0; kt2 < 2; ++kt2) {
            bf16x8 bh = *(const bf16x8*)(MThi + (size_t)col * 64 + kt2 * 32 + g * 8);
            bf16x8 bl = *(const bf16x8*)(MTlo + (size_t)col * 64 + kt2 * 32 + g * 8);
#pragma unroll
            for (int m = 0; m < 2; ++m) {
                pacc[m] = __builtin_amdgcn_mfma_f32_16x16x32_bf16(wah[m][kt2], bh, pacc[m], 0, 0, 0);
                pacc[m] = __builtin_amdgcn_mfma_f32_16x16x32_bf16(wah[m][kt2], bl, pacc[m], 0, 0, 0);
                pacc[m] = __builtin_amdgcn_mfma_f32_16x16x32_bf16(wal[m][kt2], bh, pacc[m], 0, 0, 0);
            }
        }
#pragma unroll
        for (int m = 0; m < 2; ++m)
#pragma unroll
            for (int r = 0; r < 4; ++r) {
                int row = base + m * 16 + g * 4 + r;
                float v = pacc[m][r] * (1.f / 64.f);
                float x = nf[(size_t)row * 768 + col];
                re[(size_t)row * 768 + col] = v;
                float d = x - v;
                lp = fmaf(d, d, lp);
            }
    }
    for (int o = 32; o; o >>= 1) lp += __shfl_xor(lp, o);
    if (l == 0) lred[w] = lp;
    __syncthreads();
    if (tid == 0) atomicAdd(lossac, lred[0] + lred[1] + lred[2] + lred[3]);
}

__global__ void k_loss_final(const float* __restrict__ acc, float* __restrict__ out, float invn) {
    if (threadIdx.x == 0 && blockIdx.x == 0) out[0] = acc[0] * invn;
}

// ---------------- launch ----------------
extern "C" void kernel_launch(void* const* d_in, const int* in_sizes, int n_in,
                              void* d_out, int out_size, void* d_ws, size_t ws_size,
                              hipStream_t stream) {
    const float* feature  = (const float*)d_in[0];
    const float* ppr      = (const float*)d_in[1];
    const float* edge_attr= (const float*)d_in[2];
    const float* Ws       = (const float*)d_in[3];
    const float* bs       = (const float*)d_in[4];
    const float* W1       = (const float*)d_in[5];
    const float* b1       = (const float*)d_in[6];
    const float* prelu_a  = (const float*)d_in[7];
    const float* W2       = (const float*)d_in[8];
    const float* b2       = (const float*)d_in[9];
    const float* Wp1      = (const float*)d_in[10];
    const float* bp1      = (const float*)d_in[11];
    const float* Wp2      = (const float*)d_in[12];
    const float* bp2      = (const float*)d_in[13];
    const float* memory   = (const float*)d_in[14];
    const int*   edge_index = (const int*)d_in[15];
    const int*   batch_ids  = (const int*)d_in[16];

    const int E = in_sizes[15] / 2;
    const int N = in_sizes[0] / DIN;
    const int* col = edge_index + E;

    char* ws = (char*)d_ws;
    ushort_t* Xhi  = (ushort_t*)(ws + OFF_XHI);
    ushort_t* Xlo  = (ushort_t*)(ws + OFF_XLO);
    ushort_t* Hhi  = (ushort_t*)(ws + OFF_HHI);
    ushort_t* Hlo  = (ushort_t*)(ws + OFF_HLO);
    float*    nf   = (float*)   (ws + OFF_NF);
    ushort_t* NFhi = (ushort_t*)(ws + OFF_NFHI);
    ushort_t* NFlo = (ushort_t*)(ws + OFF_NFLO);
    ushort_t* W1Thi= (ushort_t*)(ws + OFF_W1THI);
    ushort_t* W1Tlo= (ushort_t*)(ws + OFF_W1TLO);
    ushort_t* W2Thi= (ushort_t*)(ws + OFF_W2THI);
    ushort_t* W2Tlo= (ushort_t*)(ws + OFF_W2TLO);
    ushort_t* Mhi  = (ushort_t*)(ws + OFF_MHI);
    ushort_t* Mlo  = (ushort_t*)(ws + OFF_MLO);
    ushort_t* MThi = (ushort_t*)(ws + OFF_MTHI);
    ushort_t* MTlo = (ushort_t*)(ws + OFF_MTLO);
    int*   bucket = (int*)(ws + OFF_BUCKET);
    int*   counts = (int*)(ws + OFF_COUNTS);
    int*   gstart = (int*)(ws + OFF_GSTART);
    int*   gend   = (int*)(ws + OFF_GEND);
    float* lossac = (float*)(ws + OFF_LOSS);
    float* gfeatT = (float*)(ws + OFF_GFEAT);
    float* t1T    = (float*)(ws + OFF_T1);

    float* out_pooled = (float*)d_out;
    float* out_re     = (float*)d_out + NGRAPH * DOUT;
    float* out_loss   = (float*)d_out + NGRAPH * DOUT + (size_t)N * DOUT;

    (void)hipMemsetAsync(ws + ZERO_OFF, 0, ZERO_BYTES, stream);

    k_wsplit<<<dim3(768 / 32, 800 / 32), 256, 0, stream>>>(W1, W1Thi, W1Tlo, XDIM, DHID);
    k_wsplit<<<dim3(768 / 32, 768 / 32), 256, 0, stream>>>(W2, W2Thi, W2Tlo, DHID, DOUT);
    k_wsplit<<<dim3(768 / 32, 64 / 32), 256, 0, stream>>>(memory, MThi, MTlo, MEMK, DOUT);
    k_msplit<<<(MEMK * 768 + 255) / 256, 256, 0, stream>>>(memory, Mhi, Mlo, MEMK * 768);

    k_fill_bucket<<<1024, 256, 0, stream>>>(col, counts, bucket, E);
    k_aggregate<<<N, 192, 0, stream>>>(feature, edge_attr, ppr, Ws, bs, bucket, counts, Xhi, Xlo);

    k_gemm_mfma<1, 1><<<dim3(DHID / 128, N / 64), 256, 0, stream>>>(
        Xhi, Xlo, W1Thi, W1Tlo, b1, prelu_a, nullptr, Hhi, Hlo, N, DHID, XDIM);
    k_gemm_mfma<0, 2><<<dim3(DOUT / 128, N / 64), 256, 0, stream>>>(
        Hhi, Hlo, W2Thi, W2Tlo, b2, nullptr, nf, NFhi, NFlo, N, DOUT, DHID);

    k_boundaries<<<(N + 255) / 256, 256, 0, stream>>>(batch_ids, gstart, gend, N);
    k_pool<<<dim3(NGRAPH, 6), 128, 0, stream>>>(nf, gstart, gend, gfeatT);

    k_mlp_t<2><<<768, 256, 0, stream>>>(gfeatT, Wp1, bp1, t1T, nullptr);
    k_mlp_t<0><<<768, 256, 0, stream>>>(t1T, Wp2, bp2, nullptr, out_pooled);

    k_attn<<<N / 32, 256, 0, stream>>>(NFhi, NFlo, Mhi, Mlo, MThi, MTlo, nf, out_re, lossac);
    k_loss_final<<<1, 64, 0, stream>>>(lossac, out_loss, 1.f / (float)((size_t)N * DOUT));
}